// Round 8
// baseline (9485.191 us; speedup 1.0000x reference)
//
#include <hip/hip_runtime.h>

#define N_NEUR 4096
#define B_SZ   64
#define T_STEPS 128
#define N_CLS  10

typedef double d4v __attribute__((ext_vector_type(4)));
typedef int    i4v __attribute__((ext_vector_type(4)));

__device__ __forceinline__ int permb(int beta, int p) {
    return p ? ((beta & 3) * 4 + (beta >> 2)) : beta;   // self-inverse 4x4 transpose
}
__device__ __forceinline__ int Aval(int i, int k) { return ((i * 67 + k * 13) % 11) - 5; }
__device__ __forceinline__ int Bval(int k, int j) { return ((k * 29 + j * 7) % 9) - 4; }

__device__ const double lwt[7] = {0x1p-51, 0x1p-43, 0x1p-35, 0x1p-27, 0x1p-19, 0x1p-11, 0x1p-3};

// ---------------- probe: (A,B,D,byte-perm) lane maps for mfma_i32_16x16x64_i8 ----------------
__global__ void kernProbe8(int* __restrict__ out) {
    int l = threadIdx.x;
    int best = -1;
    for (int c = 0; c < 64; ++c) {
        int amap = c & 1, bmap = (c >> 1) & 1, dmap = (c >> 2) & 3, ap = (c >> 4) & 1, bp = (c >> 5) & 1;
        int ai  = amap ? (l >> 2) : (l & 15);
        int akg = amap ? (l & 3)  : (l >> 4);
        int bj  = bmap ? (l >> 2) : (l & 15);
        int bkg = bmap ? (l & 3)  : (l >> 4);
        int aw[4], bw[4];
        #pragma unroll
        for (int w = 0; w < 4; ++w) {
            int a4 = 0, b4 = 0;
            #pragma unroll
            for (int byi = 0; byi < 4; ++byi) {
                int beta = w * 4 + byi;
                int ka = akg * 16 + permb(beta, ap);
                int kb = bkg * 16 + permb(beta, bp);
                a4 |= (Aval(ai, ka) & 255) << (8 * byi);
                b4 |= (Bval(kb, bj) & 255) << (8 * byi);
            }
            aw[w] = a4; bw[w] = b4;
        }
        i4v a = {aw[0], aw[1], aw[2], aw[3]};
        i4v b = {bw[0], bw[1], bw[2], bw[3]};
        i4v d = {0, 0, 0, 0};
        d = __builtin_amdgcn_mfma_i32_16x16x64_i8(a, b, d, 0, 0, 0);
        bool ok = true;
        #pragma unroll
        for (int r = 0; r < 4; ++r) {
            int di, dj;
            if      (dmap == 0) { di = 4 * (l >> 4) + r; dj = l & 15; }
            else if (dmap == 1) { di = l & 15; dj = 4 * (l >> 4) + r; }
            else if (dmap == 2) { di = (l >> 4) + 4 * r; dj = l & 15; }
            else                { di = l & 15; dj = (l >> 4) + 4 * r; }
            int ref = 0;
            for (int k = 0; k < 64; ++k) ref += Aval(di, k) * Bval(k, dj);
            ok = ok && (d[r] == ref);
        }
        unsigned long long m = __ballot(ok);
        if (m == ~0ull && best < 0) best = c;
    }
    if (l == 0) out[0] = best;          // -1 => fall back to f64 path
}

// ---------------- probe: f64 MFMA maps (fallback path) ----------------
__global__ void kernProbeF(int* __restrict__ out) {
    int l = threadIdx.x;
    int best = -1;
    for (int c = 0; c < 16; ++c) {
        int amap = c & 1, bmap = (c >> 1) & 1, dmap = (c >> 2) & 3;
        int ai = amap ? (l >> 2) : (l & 15);
        int ak = amap ? (l & 3)  : (l >> 4);
        int bk = bmap ? (l & 3)  : (l >> 4);
        int bj = bmap ? (l >> 2) : (l & 15);
        double a = (double)(ai * 4 + ak + 1);
        double b = (double)(bk * 16 + bj + 1);
        d4v d = {0.0, 0.0, 0.0, 0.0};
        d = __builtin_amdgcn_mfma_f64_16x16x4f64(a, b, d, 0, 0, 0);
        bool ok = true;
        #pragma unroll
        for (int r = 0; r < 4; ++r) {
            int di, dj;
            if      (dmap == 0) { di = 4 * (l >> 4) + r; dj = l & 15; }
            else if (dmap == 1) { di = l & 15; dj = 4 * (l >> 4) + r; }
            else if (dmap == 2) { di = (l >> 4) + 4 * r; dj = l & 15; }
            else                { di = l & 15; dj = (l >> 4) + 4 * r; }
            double ref = 0.0;
            for (int k = 0; k < 4; ++k)
                ref += (double)(di * 4 + k + 1) * (double)(k * 16 + dj + 1);
            ok = ok && (d[r] == ref);
        }
        unsigned long long m = __ballot(ok);
        if (m == ~0ull && best < 0) best = c;
    }
    if (l == 0) out[0] = (best < 0) ? 0 : best;
}

// ---------------- pack W_res into 7 i8 limbs: A8[l][n][16c+beta] = digit_l(rint(W[n][16c+pa(beta)]*2^51)) ----------------
__global__ __launch_bounds__(256) void kernP8(const float* __restrict__ W,
                                              signed char* __restrict__ A8,
                                              const int* __restrict__ combo) {
    int c8 = combo[0];
    int ap = (c8 < 0) ? 0 : ((c8 >> 4) & 1);
    int n = blockIdx.x;
    int c = threadIdx.x;
    const float* src = W + (size_t)n * N_NEUR + 16 * c;
    long long q[16];
    #pragma unroll
    for (int beta = 0; beta < 16; ++beta)
        q[beta] = (long long)rint((double)src[permb(beta, ap)] * 0x1p51);
    size_t off = (size_t)n * N_NEUR + 16 * c;
    #pragma unroll
    for (int l = 0; l < 7; ++l) {
        int wrd[4];
        #pragma unroll
        for (int w = 0; w < 4; ++w) {
            int b4 = 0;
            #pragma unroll
            for (int byi = 0; byi < 4; ++byi) {
                long long& qq = q[w * 4 + byi];
                int d = (int)(signed char)(qq & 255);
                qq = (qq - d) >> 8;
                b4 |= (d & 255) << (8 * byi);
            }
            wrd[w] = b4;
        }
        i4v v = {wrd[0], wrd[1], wrd[2], wrd[3]};
        *(i4v*)(A8 + (size_t)l * N_NEUR * N_NEUR + off) = v;
    }
}

// ---------------- t=0 init ----------------
__global__ __launch_bounds__(256) void kernI(const float* __restrict__ x,
                                             const float* __restrict__ Win,
                                             double* __restrict__ vr,
                                             signed char* __restrict__ sf8,   // [b][m] (byte-permuted)
                                             float* __restrict__ sT,          // [n][b]
                                             const int* __restrict__ combo) {
    int c8 = combo[0];
    int bp8 = (c8 < 0) ? 0 : ((c8 >> 5) & 1);
    int idx = blockIdx.x * 256 + threadIdx.x;
    int b = idx & 63, n = idx >> 6;
    double v = (double)x[b * T_STEPS] * (double)Win[n];
    bool sp = (v >= 1.0);
    vr[idx] = sp ? 0.0 : v;
    sT[idx] = sp ? 1.0f : 0.0f;
    sf8[(size_t)b * N_NEUR + (n & ~15) + permb(n & 15, bp8)] = sp ? 1 : 0;
}

// ---------------- fused: recurrent GEMM (i8 limbs or f64 fallback) + LIF + classifier(t-1) ----------------
__global__ __launch_bounds__(1024) void kernAB(const signed char* __restrict__ A8,
                                               const float* __restrict__ Wres,
                                               const signed char* __restrict__ sf8p,
                                               const float* __restrict__ x,
                                               const float* __restrict__ Win,
                                               double* __restrict__ vr,
                                               signed char* __restrict__ sf8c,
                                               float* __restrict__ sTc,
                                               const float* __restrict__ sTp,
                                               const float* __restrict__ Wout,
                                               double* __restrict__ vc,
                                               double* __restrict__ counts,
                                               const int* __restrict__ combo,
                                               int t) {
    __shared__ double lbuf[4][1024];
    __shared__ double red[16][N_CLS];
    const int tid = threadIdx.x;
    const int wave = tid >> 6, lane = tid & 63;
    const int wb = wave & 3, wq = wave >> 2;
    const int gn0 = blockIdx.x * 16;
    const int c8 = combo[0];

    d4v accd = {0.0, 0.0, 0.0, 0.0};
    int dmap;

    if (c8 >= 0) {
        // ---------- i8 limb path ----------
        const int amap = c8 & 1, bmap = (c8 >> 1) & 1;
        dmap = (c8 >> 2) & 3;
        const int ai  = amap ? (lane >> 2) : (lane & 15);
        const int akg = amap ? (lane & 3)  : (lane >> 4);
        const int bj  = bmap ? (lane >> 2) : (lane & 15);
        const int bkg = bmap ? (lane & 3)  : (lane >> 4);

        const signed char* bbase = sf8p + (size_t)(16 * wb + bj) * N_NEUR + wq * 1024 + bkg * 16;
        i4v breg[16];
        #pragma unroll
        for (int kb = 0; kb < 16; ++kb)
            breg[kb] = *(const i4v*)(bbase + kb * 64);

        const size_t LSTR = (size_t)N_NEUR * N_NEUR;
        const signed char* abase = A8 + (size_t)(gn0 + ai) * N_NEUR + wq * 1024 + akg * 16;
        i4v ring[4];
        #pragma unroll
        for (int p = 0; p < 4; ++p)
            ring[p] = *(const i4v*)(abase + p * 64);    // it = 0..3 (limb 0)

        for (int l = 0; l < 7; ++l) {
            i4v acci = {0, 0, 0, 0};
            #pragma unroll
            for (int kb = 0; kb < 16; ++kb) {
                i4v a = ring[kb & 3];
                int itp = l * 16 + kb + 4;
                if (itp < 112)
                    ring[kb & 3] = *(const i4v*)(abase + (size_t)(itp >> 4) * LSTR + (itp & 15) * 64);
                acci = __builtin_amdgcn_mfma_i32_16x16x64_i8(a, breg[kb], acci, 0, 0, 0);
            }
            const double wl = lwt[l];
            #pragma unroll
            for (int r = 0; r < 4; ++r)
                accd[r] = fma((double)acci[r], wl, accd[r]);
        }
    } else {
        // ---------- f64 fallback (plain Wres, byte spikes) ----------
        const int c64 = combo[1];
        const int amap = c64 & 1, bmap = (c64 >> 1) & 1;
        dmap = (c64 >> 2) & 3;
        const int ai = amap ? (lane >> 2) : (lane & 15);
        const int ak = amap ? (lane & 3)  : (lane >> 4);
        const int bk = bmap ? (lane & 3)  : (lane >> 4);
        const int bj = bmap ? (lane >> 2) : (lane & 15);
        const signed char* bp = sf8p + (size_t)(16 * wb + bj) * N_NEUR + bk;
        #pragma unroll 4
        for (int q = 0; q < 256; ++q) {
            int k4 = 4 * (wq * 256 + q);
            double a  = (double)Wres[(size_t)(gn0 + ai) * N_NEUR + k4 + ak];
            double bv = (double)bp[k4];
            accd = __builtin_amdgcn_mfma_f64_16x16x4f64(a, bv, accd, 0, 0, 0);
        }
    }

    {
        const int jb = 16 * wb;
        #pragma unroll
        for (int r = 0; r < 4; ++r) {
            int di, dj;
            if      (dmap == 0) { di = 4 * (lane >> 4) + r; dj = lane & 15; }
            else if (dmap == 1) { di = lane & 15; dj = 4 * (lane >> 4) + r; }
            else if (dmap == 2) { di = (lane >> 4) + 4 * r; dj = lane & 15; }
            else                { di = lane & 15; dj = (lane >> 4) + 4 * r; }
            lbuf[wq][di * 64 + jb + dj] = accd[r];
        }
    }
    __syncthreads();

    // ---- LIF tail ----
    {
        int nl = tid >> 6, b = tid & 63;
        int n = gn0 + nl;
        size_t gidx = (size_t)n * 64 + b;
        double cur = lbuf[0][tid] + lbuf[1][tid] + lbuf[2][tid] + lbuf[3][tid]
                   + (double)x[b * T_STEPS + t] * (double)Win[n];
        double v = 0.9 * vr[gidx] + cur;
        bool sp = (v >= 1.0);
        vr[gidx] = sp ? 0.0 : v;
        sTc[gidx] = sp ? 1.0f : 0.0f;
        int bp8 = (c8 < 0) ? 0 : ((c8 >> 5) & 1);
        sf8c[(size_t)b * N_NEUR + (n & ~15) + permb(n & 15, bp8)] = sp ? 1 : 0;
    }

    // ---- classifier for step t-1, batch b = blockIdx (blocks 0..63) ----
    if (blockIdx.x < 64) {
        const int bcls = blockIdx.x;
        double part[N_CLS];
        #pragma unroll
        for (int c = 0; c < N_CLS; ++c) part[c] = 0.0;
        for (int m = tid; m < N_NEUR; m += 1024) {
            double s = (double)sTp[(size_t)m * B_SZ + bcls];
            #pragma unroll
            for (int c = 0; c < N_CLS; ++c)
                part[c] = fma(s, (double)Wout[c * N_NEUR + m], part[c]);
        }
        #pragma unroll
        for (int c = 0; c < N_CLS; ++c) {
            double v = part[c];
            for (int off = 32; off > 0; off >>= 1)
                v += __shfl_down(v, off, 64);
            if (lane == 0) red[wave][c] = v;
        }
        __syncthreads();
        if (tid < N_CLS) {
            double tot = 0.0;
            #pragma unroll
            for (int wv = 0; wv < 16; ++wv) tot += red[wv][tid];
            double v = 0.9 * vc[bcls * N_CLS + tid] + tot;
            bool sp = (v >= 1.0);
            vc[bcls * N_CLS + tid] = sp ? 0.0 : v;
            if (sp) counts[bcls * N_CLS + tid] += 1.0;
        }
    }
}

// ---------------- standalone classifier (final step) ----------------
__global__ __launch_bounds__(256) void kernC(const float* __restrict__ sT,
                                             const float* __restrict__ Wout,
                                             double* __restrict__ vc,
                                             double* __restrict__ counts) {
    int b = blockIdx.x;
    int tid = threadIdx.x;
    double part[N_CLS];
    #pragma unroll
    for (int c = 0; c < N_CLS; ++c) part[c] = 0.0;
    for (int m = tid; m < N_NEUR; m += 256) {
        double s = (double)sT[(size_t)m * B_SZ + b];
        #pragma unroll
        for (int c = 0; c < N_CLS; ++c)
            part[c] = fma(s, (double)Wout[c * N_NEUR + m], part[c]);
    }
    __shared__ double red[4][N_CLS];
    int lane = tid & 63, wv = tid >> 6;
    #pragma unroll
    for (int c = 0; c < N_CLS; ++c) {
        double v = part[c];
        for (int off = 32; off > 0; off >>= 1)
            v += __shfl_down(v, off, 64);
        if (lane == 0) red[wv][c] = v;
    }
    __syncthreads();
    if (tid < N_CLS) {
        double tot = red[0][tid] + red[1][tid] + red[2][tid] + red[3][tid];
        double v = 0.9 * vc[b * N_CLS + tid] + tot;
        bool sp = (v >= 1.0);
        vc[b * N_CLS + tid] = sp ? 0.0 : v;
        if (sp) counts[b * N_CLS + tid] += 1.0;
    }
}

__global__ void kernD(const double* __restrict__ counts, float* __restrict__ out) {
    int i = blockIdx.x * blockDim.x + threadIdx.x;
    if (i < B_SZ * N_CLS) out[i] = (float)counts[i];
}

extern "C" void kernel_launch(void* const* d_in, const int* in_sizes, int n_in,
                              void* d_out, int out_size, void* d_ws, size_t ws_size,
                              hipStream_t stream) {
    const float* x    = (const float*)d_in[0];
    const float* Win  = (const float*)d_in[1];
    const float* Wres = (const float*)d_in[2];
    const float* Wout = (const float*)d_in[3];
    float* out = (float*)d_out;

    const size_t NB = (size_t)B_SZ * N_NEUR;
    char* w = (char*)d_ws;
    double*      vr     = (double*)w;       w += NB * sizeof(double);            // 2 MB
    float*       sTa    = (float*)w;        w += NB * sizeof(float);             // 1 MB
    float*       sTb    = (float*)w;        w += NB * sizeof(float);             // 1 MB
    signed char* sf8a   = (signed char*)w;  w += NB;                             // 256 KB
    signed char* sf8b   = (signed char*)w;  w += NB;                             // 256 KB
    double*      vc     = (double*)w;       w += (size_t)B_SZ * N_CLS * sizeof(double);
    double*      counts = (double*)w;       w += (size_t)B_SZ * N_CLS * sizeof(double);
    int*         combo  = (int*)w;          w += 256;
    signed char* A8     = (signed char*)w;  // 7 x 16 MB limb planes

    size_t fixed = (size_t)(w - (char*)d_ws);
    bool fits_i8 = (ws_size >= fixed + 7ull * N_NEUR * N_NEUR + 65536);

    hipMemsetAsync(combo, 0xFF, 8, stream);           // combo[0] = -1 (i8 off by default)
    kernProbeF<<<dim3(1), 64, 0, stream>>>(combo + 1);
    if (fits_i8) {
        kernProbe8<<<dim3(1), 64, 0, stream>>>(combo);
        kernP8<<<dim3(N_NEUR), 256, 0, stream>>>(Wres, A8, combo);
    }
    hipMemsetAsync(vc, 0, 2ull * B_SZ * N_CLS * sizeof(double), stream);

    kernI<<<dim3(NB / 256), 256, 0, stream>>>(x, Win, vr, sf8a, sTa, combo);
    for (int t = 1; t < T_STEPS; ++t) {
        const signed char* sfp = (t & 1) ? sf8a : sf8b;
        signed char*       sfc = (t & 1) ? sf8b : sf8a;
        float*             sTc = (t & 1) ? sTb : sTa;
        const float*       sTp = (t & 1) ? sTa : sTb;
        kernAB<<<dim3(256), 1024, 0, stream>>>(A8, Wres, sfp, x, Win, vr, sfc, sTc, sTp,
                                               Wout, vc, counts, combo, t);
    }
    kernC<<<dim3(B_SZ), 256, 0, stream>>>(sTb, Wout, vc, counts);  // t = 127 (odd -> sTb)
    kernD<<<dim3(3), 256, 0, stream>>>(counts, out);
}

// Round 9
// 8995.786 us; speedup vs baseline: 1.0544x; 1.0544x over previous
//
#include <hip/hip_runtime.h>

#define N_NEUR 4096
#define B_SZ   64
#define T_STEPS 128
#define N_CLS  10

typedef double d4v __attribute__((ext_vector_type(4)));
typedef int    i4v __attribute__((ext_vector_type(4)));

__device__ __forceinline__ int Aval(int i, int k) { return ((i * 67 + k * 13) % 11) - 5; }
__device__ __forceinline__ int Bval(int k, int j) { return ((k * 29 + j * 7) % 9) - 4; }

__device__ const double lwt[7] = {0x1p-51, 0x1p-43, 0x1p-35, 0x1p-27, 0x1p-19, 0x1p-11, 0x1p-3};

// byte(beta in 0..15, group g=lane>>4) -> k offset within a 64-k window
__device__ __forceinline__ int kfwd(int m, int g, int b) {
    switch (m & 7) {
        case 0:  return 16 * g + b;                          // contiguous
        case 1:  return 16 * g + 4 * (b & 3) + (b >> 2);     // 4x4 transpose
        case 2:  return 8 * g + (b & 7) + 32 * (b >> 3);     // two K=32 halves (CDNA3-style)
        case 3:  return 4 * g + (b & 3) + 16 * (b >> 2);     // four K=16 passes
        case 4:  return 4 * b + g;                           // byte-major
        case 5:  return 16 * g + ((b + 8) & 15);             // dword-pair swap
        case 6:  return 16 * g + 2 * (b & 7) + (b >> 3);     // pair interleave
        default: return 16 * g + 8 * (b & 1) + (b >> 1);     // odd/even split
    }
}
// window-k -> position offset (16g + beta); inverse of kfwd
__device__ __forceinline__ int kinvpos(int m, int kw) {
    switch (m & 7) {
        case 0:  return kw;
        case 1:  { int g = kw >> 4, r = kw & 15; return 16 * g + 4 * (r & 3) + (r >> 2); }
        case 2:  { int hi = kw >> 5, rem = kw & 31; return 16 * (rem >> 3) + 8 * hi + (rem & 7); }
        case 3:  { int q = kw >> 4, rem = kw & 15; return 16 * (rem >> 2) + 4 * q + (rem & 3); }
        case 4:  return 16 * (kw & 3) + (kw >> 2);
        case 5:  { int g = kw >> 4, r = kw & 15; return 16 * g + ((r + 8) & 15); }
        case 6:  { int g = kw >> 4, r = kw & 15; return 16 * g + 8 * (r & 1) + (r >> 1); }
        default: { int g = kw >> 4, r = kw & 15; return 16 * g + 2 * (r & 7) + (r >> 3); }
    }
}

// ---------------- parallel probe: one combo per block, atomicMin on success ----------------
__global__ void kernProbe8(int* __restrict__ out) {
    const int c = blockIdx.x;                 // 0..255
    const int ma = c & 7, mb = (c >> 3) & 7, dmap = (c >> 6) & 3;
    const int l = threadIdx.x;
    const int i = l & 15, g = l >> 4;
    int aw[4], bw[4];
    #pragma unroll
    for (int w = 0; w < 4; ++w) {
        int a4 = 0, b4 = 0;
        #pragma unroll
        for (int byi = 0; byi < 4; ++byi) {
            int beta = w * 4 + byi;
            a4 |= (Aval(i, kfwd(ma, g, beta)) & 255) << (8 * byi);
            b4 |= (Bval(kfwd(mb, g, beta), i) & 255) << (8 * byi);
        }
        aw[w] = a4; bw[w] = b4;
    }
    i4v a = {aw[0], aw[1], aw[2], aw[3]};
    i4v b = {bw[0], bw[1], bw[2], bw[3]};
    i4v d = {0, 0, 0, 0};
    d = __builtin_amdgcn_mfma_i32_16x16x64_i8(a, b, d, 0, 0, 0);
    bool ok = true;
    #pragma unroll
    for (int r = 0; r < 4; ++r) {
        int di, dj;
        if      (dmap == 0) { di = 4 * (l >> 4) + r; dj = l & 15; }
        else if (dmap == 1) { di = l & 15; dj = 4 * (l >> 4) + r; }
        else if (dmap == 2) { di = (l >> 4) + 4 * r; dj = l & 15; }
        else                { di = l & 15; dj = (l >> 4) + 4 * r; }
        int ref = 0;
        for (int k = 0; k < 64; ++k) ref += Aval(di, k) * Bval(k, dj);
        ok = ok && (d[r] == ref);
    }
    unsigned long long m = __ballot(ok);
    if (l == 0 && m == ~0ull) atomicMin(out, c);
}

// ---------------- probe: f64 MFMA maps (fallback path) ----------------
__global__ void kernProbeF(int* __restrict__ out) {
    int l = threadIdx.x;
    int best = -1;
    for (int c = 0; c < 16; ++c) {
        int amap = c & 1, bmap = (c >> 1) & 1, dmap = (c >> 2) & 3;
        int ai = amap ? (l >> 2) : (l & 15);
        int ak = amap ? (l & 3)  : (l >> 4);
        int bk = bmap ? (l & 3)  : (l >> 4);
        int bj = bmap ? (l >> 2) : (l & 15);
        double a = (double)(ai * 4 + ak + 1);
        double b = (double)(bk * 16 + bj + 1);
        d4v d = {0.0, 0.0, 0.0, 0.0};
        d = __builtin_amdgcn_mfma_f64_16x16x4f64(a, b, d, 0, 0, 0);
        bool ok = true;
        #pragma unroll
        for (int r = 0; r < 4; ++r) {
            int di, dj;
            if      (dmap == 0) { di = 4 * (l >> 4) + r; dj = l & 15; }
            else if (dmap == 1) { di = l & 15; dj = 4 * (l >> 4) + r; }
            else if (dmap == 2) { di = (l >> 4) + 4 * r; dj = l & 15; }
            else                { di = l & 15; dj = (l >> 4) + 4 * r; }
            double ref = 0.0;
            for (int k = 0; k < 4; ++k)
                ref += (double)(di * 4 + k + 1) * (double)(k * 16 + dj + 1);
            ok = ok && (d[r] == ref);
        }
        unsigned long long m = __ballot(ok);
        if (m == ~0ull && best < 0) best = c;
    }
    if (l == 0) out[0] = (best < 0) ? 0 : best;
}

// ---------------- pack W_res into 7 i8 limb planes (A-fragment position order) ----------------
__global__ __launch_bounds__(256) void kernP8(const float* __restrict__ W,
                                              signed char* __restrict__ A8,
                                              const int* __restrict__ combo) {
    int c8 = combo[0];
    int ma = (c8 >= 0 && c8 < 256) ? (c8 & 7) : 0;
    int n = blockIdx.x;
    int t = threadIdx.x;
    int w = t >> 2, g = t & 3;                 // 64-k window, k-group
    const float* src = W + (size_t)n * N_NEUR + 64 * w;
    long long q[16];
    #pragma unroll
    for (int beta = 0; beta < 16; ++beta)
        q[beta] = (long long)rint((double)src[kfwd(ma, g, beta)] * 0x1p51);
    size_t off = (size_t)n * N_NEUR + 64 * w + 16 * g;
    #pragma unroll
    for (int l = 0; l < 7; ++l) {
        int wrd[4];
        #pragma unroll
        for (int wd = 0; wd < 4; ++wd) {
            int b4 = 0;
            #pragma unroll
            for (int byi = 0; byi < 4; ++byi) {
                long long& qq = q[wd * 4 + byi];
                int d = (int)(signed char)(qq & 255);
                qq = (qq - d) >> 8;
                b4 |= (d & 255) << (8 * byi);
            }
            wrd[wd] = b4;
        }
        i4v v = {wrd[0], wrd[1], wrd[2], wrd[3]};
        *(i4v*)(A8 + (size_t)l * N_NEUR * N_NEUR + off) = v;
    }
}

__device__ __forceinline__ size_t spike_pos(int b, int n, int c8) {
    int kw = n & 63;
    int po = (c8 >= 0 && c8 < 256) ? kinvpos((c8 >> 3) & 7, kw) : kw;
    return (size_t)b * N_NEUR + (n & ~63) + po;
}

// ---------------- t=0 init ----------------
__global__ __launch_bounds__(256) void kernI(const float* __restrict__ x,
                                             const float* __restrict__ Win,
                                             double* __restrict__ vr,
                                             signed char* __restrict__ sf8,
                                             float* __restrict__ sT,
                                             const int* __restrict__ combo) {
    int c8 = combo[0];
    int idx = blockIdx.x * 256 + threadIdx.x;
    int b = idx & 63, n = idx >> 6;
    double v = (double)x[b * T_STEPS] * (double)Win[n];
    bool sp = (v >= 1.0);
    vr[idx] = sp ? 0.0 : v;
    sT[idx] = sp ? 1.0f : 0.0f;
    sf8[spike_pos(b, n, c8)] = sp ? 1 : 0;
}

// ---------------- fused: recurrent GEMM (i8 limbs or f64 fallback) + LIF + classifier(t-1) ----------------
__global__ __launch_bounds__(1024) void kernAB(const signed char* __restrict__ A8,
                                               const float* __restrict__ Wres,
                                               const signed char* __restrict__ sf8p,
                                               const float* __restrict__ x,
                                               const float* __restrict__ Win,
                                               double* __restrict__ vr,
                                               signed char* __restrict__ sf8c,
                                               float* __restrict__ sTc,
                                               const float* __restrict__ sTp,
                                               const float* __restrict__ Wout,
                                               double* __restrict__ vc,
                                               double* __restrict__ counts,
                                               const int* __restrict__ combo,
                                               int t) {
    __shared__ double lbuf[4][1024];
    __shared__ double red[16][N_CLS];
    const int tid = threadIdx.x;
    const int wave = tid >> 6, lane = tid & 63;
    const int wb = wave & 3, wq = wave >> 2;
    const int gn0 = blockIdx.x * 16;
    const int c8 = combo[0];
    const bool i8ok = (c8 >= 0 && c8 < 256);

    d4v accd = {0.0, 0.0, 0.0, 0.0};
    int dmap;

    if (i8ok) {
        dmap = (c8 >> 6) & 3;
        const int ai = lane & 15, akg = lane >> 4;
        const int bj = lane & 15, bkg = lane >> 4;

        const signed char* bbase = sf8p + (size_t)(16 * wb + bj) * N_NEUR + wq * 1024 + bkg * 16;
        i4v breg[16];
        #pragma unroll
        for (int kb = 0; kb < 16; ++kb)
            breg[kb] = *(const i4v*)(bbase + kb * 64);

        const size_t LSTR = (size_t)N_NEUR * N_NEUR;
        const signed char* abase = A8 + (size_t)(gn0 + ai) * N_NEUR + wq * 1024 + akg * 16;
        i4v ring[4];
        #pragma unroll
        for (int p = 0; p < 4; ++p)
            ring[p] = *(const i4v*)(abase + p * 64);

        for (int l = 0; l < 7; ++l) {
            i4v acci = {0, 0, 0, 0};
            #pragma unroll
            for (int kb = 0; kb < 16; ++kb) {
                i4v a = ring[kb & 3];
                int itp = l * 16 + kb + 4;
                if (itp < 112)
                    ring[kb & 3] = *(const i4v*)(abase + (size_t)(itp >> 4) * LSTR + (itp & 15) * 64);
                acci = __builtin_amdgcn_mfma_i32_16x16x64_i8(a, breg[kb], acci, 0, 0, 0);
            }
            const double wl = lwt[l];
            #pragma unroll
            for (int r = 0; r < 4; ++r)
                accd[r] = fma((double)acci[r], wl, accd[r]);
        }
    } else {
        const int c64 = combo[1];
        const int amap = c64 & 1, bmap = (c64 >> 1) & 1;
        dmap = (c64 >> 2) & 3;
        const int ai = amap ? (lane >> 2) : (lane & 15);
        const int ak = amap ? (lane & 3)  : (lane >> 4);
        const int bk = bmap ? (lane & 3)  : (lane >> 4);
        const int bj = bmap ? (lane >> 2) : (lane & 15);
        const signed char* bp = sf8p + (size_t)(16 * wb + bj) * N_NEUR + bk;
        #pragma unroll 4
        for (int q = 0; q < 256; ++q) {
            int k4 = 4 * (wq * 256 + q);
            double a  = (double)Wres[(size_t)(gn0 + ai) * N_NEUR + k4 + ak];
            double bv = (double)bp[k4];
            accd = __builtin_amdgcn_mfma_f64_16x16x4f64(a, bv, accd, 0, 0, 0);
        }
    }

    {
        const int jb = 16 * wb;
        #pragma unroll
        for (int r = 0; r < 4; ++r) {
            int di, dj;
            if      (dmap == 0) { di = 4 * (lane >> 4) + r; dj = lane & 15; }
            else if (dmap == 1) { di = lane & 15; dj = 4 * (lane >> 4) + r; }
            else if (dmap == 2) { di = (lane >> 4) + 4 * r; dj = lane & 15; }
            else                { di = lane & 15; dj = (lane >> 4) + 4 * r; }
            lbuf[wq][di * 64 + jb + dj] = accd[r];
        }
    }
    __syncthreads();

    {
        int nl = tid >> 6, b = tid & 63;
        int n = gn0 + nl;
        size_t gidx = (size_t)n * 64 + b;
        double cur = lbuf[0][tid] + lbuf[1][tid] + lbuf[2][tid] + lbuf[3][tid]
                   + (double)x[b * T_STEPS + t] * (double)Win[n];
        double v = 0.9 * vr[gidx] + cur;
        bool sp = (v >= 1.0);
        vr[gidx] = sp ? 0.0 : v;
        sTc[gidx] = sp ? 1.0f : 0.0f;
        sf8c[spike_pos(b, n, c8)] = sp ? 1 : 0;
    }

    if (blockIdx.x < 64) {
        const int bcls = blockIdx.x;
        double part[N_CLS];
        #pragma unroll
        for (int c = 0; c < N_CLS; ++c) part[c] = 0.0;
        for (int m = tid; m < N_NEUR; m += 1024) {
            double s = (double)sTp[(size_t)m * B_SZ + bcls];
            #pragma unroll
            for (int c = 0; c < N_CLS; ++c)
                part[c] = fma(s, (double)Wout[c * N_NEUR + m], part[c]);
        }
        #pragma unroll
        for (int c = 0; c < N_CLS; ++c) {
            double v = part[c];
            for (int off = 32; off > 0; off >>= 1)
                v += __shfl_down(v, off, 64);
            if (lane == 0) red[wave][c] = v;
        }
        __syncthreads();
        if (tid < N_CLS) {
            double tot = 0.0;
            #pragma unroll
            for (int wv = 0; wv < 16; ++wv) tot += red[wv][tid];
            double v = 0.9 * vc[bcls * N_CLS + tid] + tot;
            bool sp = (v >= 1.0);
            vc[bcls * N_CLS + tid] = sp ? 0.0 : v;
            if (sp) counts[bcls * N_CLS + tid] += 1.0;
        }
    }
}

// ---------------- standalone classifier (final step) ----------------
__global__ __launch_bounds__(256) void kernC(const float* __restrict__ sT,
                                             const float* __restrict__ Wout,
                                             double* __restrict__ vc,
                                             double* __restrict__ counts) {
    int b = blockIdx.x;
    int tid = threadIdx.x;
    double part[N_CLS];
    #pragma unroll
    for (int c = 0; c < N_CLS; ++c) part[c] = 0.0;
    for (int m = tid; m < N_NEUR; m += 256) {
        double s = (double)sT[(size_t)m * B_SZ + b];
        #pragma unroll
        for (int c = 0; c < N_CLS; ++c)
            part[c] = fma(s, (double)Wout[c * N_NEUR + m], part[c]);
    }
    __shared__ double red[4][N_CLS];
    int lane = tid & 63, wv = tid >> 6;
    #pragma unroll
    for (int c = 0; c < N_CLS; ++c) {
        double v = part[c];
        for (int off = 32; off > 0; off >>= 1)
            v += __shfl_down(v, off, 64);
        if (lane == 0) red[wv][c] = v;
    }
    __syncthreads();
    if (tid < N_CLS) {
        double tot = red[0][tid] + red[1][tid] + red[2][tid] + red[3][tid];
        double v = 0.9 * vc[b * N_CLS + tid] + tot;
        bool sp = (v >= 1.0);
        vc[b * N_CLS + tid] = sp ? 0.0 : v;
        if (sp) counts[b * N_CLS + tid] += 1.0;
    }
}

__global__ void kernD(const double* __restrict__ counts, float* __restrict__ out) {
    int i = blockIdx.x * blockDim.x + threadIdx.x;
    if (i < B_SZ * N_CLS) out[i] = (float)counts[i];
}

extern "C" void kernel_launch(void* const* d_in, const int* in_sizes, int n_in,
                              void* d_out, int out_size, void* d_ws, size_t ws_size,
                              hipStream_t stream) {
    const float* x    = (const float*)d_in[0];
    const float* Win  = (const float*)d_in[1];
    const float* Wres = (const float*)d_in[2];
    const float* Wout = (const float*)d_in[3];
    float* out = (float*)d_out;

    const size_t NB = (size_t)B_SZ * N_NEUR;
    char* w = (char*)d_ws;
    double*      vr     = (double*)w;       w += NB * sizeof(double);
    float*       sTa    = (float*)w;        w += NB * sizeof(float);
    float*       sTb    = (float*)w;        w += NB * sizeof(float);
    signed char* sf8a   = (signed char*)w;  w += NB;
    signed char* sf8b   = (signed char*)w;  w += NB;
    double*      vc     = (double*)w;       w += (size_t)B_SZ * N_CLS * sizeof(double);
    double*      counts = (double*)w;       w += (size_t)B_SZ * N_CLS * sizeof(double);
    int*         combo  = (int*)w;          w += 256;
    signed char* A8     = (signed char*)w;  // 7 x 16 MB limb planes

    size_t fixed = (size_t)(w - (char*)d_ws);
    bool fits_i8 = (ws_size >= fixed + 7ull * N_NEUR * N_NEUR + 65536);

    hipMemsetAsync(combo, 0x7F, 8, stream);   // combo[0] = huge (invalid) until probe hits
    kernProbeF<<<dim3(1), 64, 0, stream>>>(combo + 1);
    if (fits_i8) {
        kernProbe8<<<dim3(256), 64, 0, stream>>>(combo);
        kernP8<<<dim3(N_NEUR), 256, 0, stream>>>(Wres, A8, combo);
    }
    hipMemsetAsync(vc, 0, 2ull * B_SZ * N_CLS * sizeof(double), stream);

    kernI<<<dim3(NB / 256), 256, 0, stream>>>(x, Win, vr, sf8a, sTa, combo);
    for (int t = 1; t < T_STEPS; ++t) {
        const signed char* sfp = (t & 1) ? sf8a : sf8b;
        signed char*       sfc = (t & 1) ? sf8b : sf8a;
        float*             sTc = (t & 1) ? sTb : sTa;
        const float*       sTp = (t & 1) ? sTa : sTb;
        kernAB<<<dim3(256), 1024, 0, stream>>>(A8, Wres, sfp, x, Win, vr, sfc, sTc, sTp,
                                               Wout, vc, counts, combo, t);
    }
    kernC<<<dim3(B_SZ), 256, 0, stream>>>(sTb, Wout, vc, counts);  // t = 127 (odd -> sTb)
    kernD<<<dim3(3), 256, 0, stream>>>(counts, out);
}